// Round 1
// baseline (1758.526 us; speedup 1.0000x reference)
//
#include <hip/hip_runtime.h>

#define EPS 1e-5f
#define SLOPE 0.01f

// One thread per output row. A-tile (gather + concat + optional BN/LReLU of
// gathered x) staged into LDS in K-chunks; W read wave-uniformly (s_load path).
template<int ROWS, int KC, int STRIDE, int K_TOTAL, int XD, int SD,
         int C_OUT, int C_TILE, bool APPLY_BN, bool STATS>
__global__ __launch_bounds__(ROWS)
void gemm_stage(const float* __restrict__ xsrc,   // gathered table [*, XD]
                const float* __restrict__ skip,   // [N, SD]
                const int*   __restrict__ idx,    // [N]
                const float* __restrict__ W,      // [K_TOTAL, C_OUT]
                const float* __restrict__ bias,   // [C_OUT]
                const float* __restrict__ bn_scale, // [XD] or null
                const float* __restrict__ bn_shift, // [XD] or null
                float*       __restrict__ out,    // [N, C_OUT]
                float*       __restrict__ stat_sum,
                float*       __restrict__ stat_sq)
{
    __shared__ float lds[ROWS * STRIDE];
    __shared__ int   lidx[ROWS];
    const int tid  = threadIdx.x;
    const int row0 = blockIdx.x * ROWS;
    const int j0   = blockIdx.y * C_TILE;

    lidx[tid] = idx[row0 + tid];

    float acc[C_TILE];
#pragma unroll
    for (int j = 0; j < C_TILE; ++j) acc[j] = 0.f;

    for (int kb = 0; kb < K_TOTAL; kb += KC) {
        __syncthreads();
        // cooperative stage of A chunk [ROWS x KC]
        for (int i = tid; i < ROWS * KC; i += ROWS) {
            int r  = i / KC;
            int k  = i - r * KC;
            int kg = kb + k;
            float v;
            if (kg < XD) {
                v = xsrc[lidx[r] * XD + kg];
                if (APPLY_BN) {
                    v = fmaf(v, bn_scale[kg], bn_shift[kg]);
                    v = v >= 0.f ? v : SLOPE * v;
                }
            } else {
                v = skip[(row0 + r) * SD + (kg - XD)];
            }
            lds[r * STRIDE + k] = v;
        }
        __syncthreads();
#pragma unroll 2
        for (int k = 0; k < KC; ++k) {
            float a = lds[tid * STRIDE + k];
            const float* wrow = W + (kb + k) * C_OUT + j0;  // wave-uniform
#pragma unroll
            for (int j = 0; j < C_TILE; ++j)
                acc[j] = fmaf(a, wrow[j], acc[j]);
        }
    }

#pragma unroll
    for (int j = 0; j < C_TILE; ++j) acc[j] += bias[j0 + j];

    // write output row
    {
        float* orow = out + (row0 + tid) * C_OUT + j0;
#pragma unroll
        for (int j = 0; j < C_TILE; ++j) orow[j] = acc[j];
    }

    if (STATS) {
        const int lane = tid & 63;
#pragma unroll
        for (int j = 0; j < C_TILE; ++j) {
            float s = acc[j];
            float q = s * s;
#pragma unroll
            for (int m = 32; m >= 1; m >>= 1) {
                s += __shfl_xor(s, m, 64);
                q += __shfl_xor(q, m, 64);
            }
            if (lane == 0) {
                atomicAdd(&stat_sum[j0 + j], s);
                atomicAdd(&stat_sq[j0 + j], q);
            }
        }
    }
}

__global__ void finalize_bn(const float* __restrict__ sum,
                            const float* __restrict__ sq,
                            const float* __restrict__ g,
                            const float* __restrict__ be,
                            float* __restrict__ scale,
                            float* __restrict__ shift,
                            int C, float invN)
{
    int c = blockIdx.x * blockDim.x + threadIdx.x;
    if (c < C) {
        float m   = sum[c] * invN;
        float var = fmaf(-m, m, sq[c] * invN);
        float rs  = rsqrtf(var + EPS);
        float sc  = rs * g[c];
        scale[c] = sc;
        shift[c] = fmaf(-m, sc, be[c]);
    }
}

extern "C" void kernel_launch(void* const* d_in, const int* in_sizes, int n_in,
                              void* d_out, int out_size, void* d_ws, size_t ws_size,
                              hipStream_t stream) {
    const float* feats = (const float*)d_in[0];
    const float* skip1 = (const float*)d_in[1];
    const float* skip2 = (const float*)d_in[2];
    const float* skip3 = (const float*)d_in[3];
    const int*   idx1  = (const int*)d_in[4];
    const int*   idx2  = (const int*)d_in[5];
    const int*   idx3  = (const int*)d_in[6];
    const float* W1    = (const float*)d_in[7];
    const float* b1    = (const float*)d_in[8];
    const float* g1    = (const float*)d_in[9];
    const float* be1   = (const float*)d_in[10];
    const float* W2    = (const float*)d_in[11];
    const float* b2    = (const float*)d_in[12];
    const float* g2    = (const float*)d_in[13];
    const float* be2   = (const float*)d_in[14];
    const float* W3    = (const float*)d_in[15];
    const float* b3    = (const float*)d_in[16];

    float* ws     = (float*)d_ws;
    float* sum1   = ws + 0;
    float* sq1    = ws + 256;
    float* scale1 = ws + 512;
    float* shift1 = ws + 768;
    float* sum2   = ws + 1024;
    float* sq2    = ws + 1280;
    float* scale2 = ws + 1536;
    float* shift2 = ws + 1792;
    float* y1     = ws + 2048;                  // 16384*129
    float* y2     = y1 + 16384 * 129;           // 65536*64
    float* outp   = (float*)d_out;

    hipMemsetAsync(ws, 0, 2048 * sizeof(float), stream);

    // stage 1: 16384 rows, K=770 (258 feats + 512 skip3), C=129, stats on
    gemm_stage<128, 70, 71, 770, 258, 512, 129, 43, false, true>
        <<<dim3(16384 / 128, 3), 128, 0, stream>>>(
            feats, skip3, idx1, W1, b1, nullptr, nullptr, y1, sum1, sq1);

    finalize_bn<<<1, 192, 0, stream>>>(sum1, sq1, g1, be1, scale1, shift1,
                                       129, 1.f / 16384.f);

    // stage 2: 65536 rows, K=385 (129 y1+BN+LReLU + 256 skip2), C=64, stats on
    gemm_stage<128, 77, 79, 385, 129, 256, 64, 64, true, true>
        <<<dim3(65536 / 128, 1), 128, 0, stream>>>(
            y1, skip2, idx2, W2, b2, scale1, shift1, y2, sum2, sq2);

    finalize_bn<<<1, 64, 0, stream>>>(sum2, sq2, g2, be2, scale2, shift2,
                                      64, 1.f / 65536.f);

    // stage 3: 262144 rows, K=192 (64 y2+BN+LReLU + 128 skip1), C=34, no BN
    gemm_stage<128, 64, 65, 192, 64, 128, 34, 34, true, false>
        <<<dim3(262144 / 128, 1), 128, 0, stream>>>(
            y2, skip1, idx3, W3, b3, scale2, shift2, outp, nullptr, nullptr);
}

// Round 2
// 195.171 us; speedup vs baseline: 9.0102x; 9.0102x over previous
//
#include <hip/hip_runtime.h>

#define EPS 1e-5f
#define SLOPE 0.01f

typedef __attribute__((ext_vector_type(2))) float f32x2;
typedef __attribute__((ext_vector_type(4))) float f32x4;
typedef __attribute__((ext_vector_type(8))) short bf16x8;

__device__ __forceinline__ short f2bf(float f) {
    unsigned u = __float_as_uint(f);
    unsigned r = (u + 0x7FFFu + ((u >> 16) & 1u)) >> 16;
    return (short)r;
}
__device__ __forceinline__ float lrelu(float v) { return v >= 0.f ? v : SLOPE * v; }

// ---------------------------------------------------------------------------
// Wt prep: transpose W -> Wt[n][kv] (bf16), zero-padded in both n and kv.
// Virtual-K layouts (32-aligned regions; pad rows are zero so A pad is free):
//  S1: kv 0..257 = W1 rows 0..257 (feats), 258..287 = 0, 288..799 = rows 258..769
//  S2: kv 0..128 = W2 rows 0..128 (y1),    129..159 = 0, 160..415 = rows 129..384
//  S3: kv 0..191 = W3 rows (exact, no pad)
// Also zeros the 2048-float stats block each call.
// ---------------------------------------------------------------------------
__global__ void prep(const float* __restrict__ W1, const float* __restrict__ W2,
                     const float* __restrict__ W3,
                     short* __restrict__ Wt1, short* __restrict__ Wt2,
                     short* __restrict__ Wt3, float* __restrict__ stats)
{
    int id = blockIdx.x * 256 + threadIdx.x;
    if (id < 2048) stats[id] = 0.f;
    if (id < 144 * 800) {
        int n = id / 800, kv = id - n * 800;
        float v = 0.f; int ks = -1;
        if (kv < 258) ks = kv; else if (kv >= 288) ks = 258 + (kv - 288);
        if (ks >= 0 && n < 129) v = W1[ks * 129 + n];
        Wt1[n * 800 + kv] = f2bf(v);
    }
    if (id < 64 * 416) {
        int n = id / 416, kv = id - n * 416;
        float v = 0.f; int ks = -1;
        if (kv < 129) ks = kv; else if (kv >= 160) ks = 129 + (kv - 160);
        if (ks >= 0) v = W2[ks * 64 + n];
        Wt2[n * 416 + kv] = f2bf(v);
    }
    if (id < 48 * 192) {
        int n = id / 192, kv = id - n * 192;
        float v = 0.f;
        if (n < 34) v = W3[kv * 34 + n];
        Wt3[n * 192 + kv] = f2bf(v);
    }
}

// ---------------------------------------------------------------------------
// MFMA stage. 256 threads = 4 waves; each wave owns 16 output rows.
// A frags: per-lane direct global fp32 loads (row = gather via idx, or skip row)
// converted to bf16 in-register. B frags: 16B loads from Wt[n][kv] (L2-hot).
// mfma_f32_16x16x32_bf16: A lane l -> row l&15, k=(l>>4)*8+e;
//                         B lane l -> col l&15, k=(l>>4)*8+e (Wt is B^T);
//                         D lane l -> col l&15, row=(l>>4)*4+reg.
// ---------------------------------------------------------------------------
template<int XD, int XVALID, int XT, int SD, int ST, int NT, int NVALID, int OD,
         int XALIGN, bool BN, bool STATS>
__global__ __launch_bounds__(256)
void mfma_stage(const float* __restrict__ xsrc, const float* __restrict__ skip,
                const int* __restrict__ idx, const short* __restrict__ Wt,
                const float* __restrict__ bias,
                const float* __restrict__ bnsc, const float* __restrict__ bnsh,
                float* __restrict__ out, float* __restrict__ ssum,
                float* __restrict__ ssq)
{
    constexpr int KV = 32 * (XT + ST);
    constexpr int NPAD = NT * 16;
    __shared__ float ls[2 * NPAD];

    const int tid = threadIdx.x;
    const int wave = tid >> 6, lane = tid & 63;
    const int lr = lane & 15;                    // A row-in-16 / D col
    const int kg = lane >> 4;                    // k-group
    const int row16 = (blockIdx.x * 4 + wave) * 16;
    const int myrow = row16 + lr;
    const int grow = idx[myrow];
    const float* xrow = xsrc + grow * XD;
    const float* srow = skip + myrow * SD;
    const short* wtl = Wt + lr * KV;

    if (STATS) {
        for (int i = tid; i < 2 * NPAD; i += 256) ls[i] = 0.f;
        __syncthreads();
    }

    f32x4 acc[NT];
#pragma unroll
    for (int nt = 0; nt < NT; ++nt) acc[nt] = (f32x4){0.f, 0.f, 0.f, 0.f};

    // ---- x region (gathered rows, optional BN+LReLU of previous stage) ----
#pragma unroll
    for (int t = 0; t < XT; ++t) {
        const int kb = t * 32 + kg * 8;
        float v[8];
        if ((t + 1) * 32 <= XVALID) {            // fully-valid tile (compile-time)
            if (XALIGN >= 16) {
                f32x4 a0 = *(const f32x4*)(xrow + kb);
                f32x4 a1 = *(const f32x4*)(xrow + kb + 4);
                v[0]=a0[0]; v[1]=a0[1]; v[2]=a0[2]; v[3]=a0[3];
                v[4]=a1[0]; v[5]=a1[1]; v[6]=a1[2]; v[7]=a1[3];
            } else if (XALIGN >= 8) {
#pragma unroll
                for (int h = 0; h < 4; ++h) {
                    f32x2 a0 = *(const f32x2*)(xrow + kb + 2 * h);
                    v[2*h] = a0[0]; v[2*h+1] = a0[1];
                }
            } else {
#pragma unroll
                for (int e = 0; e < 8; ++e) v[e] = xrow[kb + e];
            }
            if (BN) {
                f32x4 c0 = *(const f32x4*)(bnsc + kb);
                f32x4 c1 = *(const f32x4*)(bnsc + kb + 4);
                f32x4 h0 = *(const f32x4*)(bnsh + kb);
                f32x4 h1 = *(const f32x4*)(bnsh + kb + 4);
#pragma unroll
                for (int e = 0; e < 4; ++e) {
                    v[e]     = lrelu(fmaf(v[e],     c0[e], h0[e]));
                    v[e + 4] = lrelu(fmaf(v[e + 4], c1[e], h1[e]));
                }
            }
        } else {                                 // partial boundary tile
#pragma unroll
            for (int e = 0; e < 8; ++e) {
                int ks = kb + e;
                float f = 0.f;
                if (ks < XVALID) {
                    f = xrow[ks];
                    if (BN) f = lrelu(fmaf(f, bnsc[ks], bnsh[ks]));
                }
                v[e] = f;
            }
        }
        bf16x8 a;
#pragma unroll
        for (int e = 0; e < 8; ++e) a[e] = f2bf(v[e]);
        const short* wk = wtl + kb;
#pragma unroll
        for (int nt = 0; nt < NT; ++nt) {
            bf16x8 b = *(const bf16x8*)(wk + nt * 16 * KV);
            acc[nt] = __builtin_amdgcn_mfma_f32_16x16x32_bf16(a, b, acc[nt], 0, 0, 0);
        }
    }

    // ---- skip region (own row, always aligned & fully valid) ----
#pragma unroll
    for (int t = 0; t < ST; ++t) {
        const int kb = t * 32 + kg * 8;
        f32x4 a0 = *(const f32x4*)(srow + kb);
        f32x4 a1 = *(const f32x4*)(srow + kb + 4);
        bf16x8 a;
#pragma unroll
        for (int e = 0; e < 4; ++e) { a[e] = f2bf(a0[e]); a[e + 4] = f2bf(a1[e]); }
        const short* wk = wtl + XT * 32 + kb;
#pragma unroll
        for (int nt = 0; nt < NT; ++nt) {
            bf16x8 b = *(const bf16x8*)(wk + nt * 16 * KV);
            acc[nt] = __builtin_amdgcn_mfma_f32_16x16x32_bf16(a, b, acc[nt], 0, 0, 0);
        }
    }

    // ---- bias, store, stats ----
#pragma unroll
    for (int nt = 0; nt < NT; ++nt) {
        const int n = nt * 16 + lr;
        const float bv = (n < NVALID) ? bias[n] : 0.f;
        f32x4 y = acc[nt];
#pragma unroll
        for (int r = 0; r < 4; ++r) y[r] += bv;
        if (n < NVALID) {
#pragma unroll
            for (int r = 0; r < 4; ++r)
                out[(row16 + kg * 4 + r) * OD + n] = y[r];
        }
        if (STATS) {
            float s = y[0] + y[1] + y[2] + y[3];
            float q = y[0]*y[0] + y[1]*y[1] + y[2]*y[2] + y[3]*y[3];
            s += __shfl_xor(s, 16, 64);
            s += __shfl_xor(s, 32, 64);
            q += __shfl_xor(q, 16, 64);
            q += __shfl_xor(q, 32, 64);
            if (lane < 16) {
                atomicAdd(&ls[n], s);
                atomicAdd(&ls[NPAD + n], q);
            }
        }
    }
    if (STATS) {
        __syncthreads();
        if (tid < NPAD) {
            atomicAdd(&ssum[tid], ls[tid]);
            atomicAdd(&ssq[tid], ls[NPAD + tid]);
        }
    }
}

__global__ void finalize_bn(const float* __restrict__ sum,
                            const float* __restrict__ sq,
                            const float* __restrict__ g,
                            const float* __restrict__ be,
                            float* __restrict__ scale,
                            float* __restrict__ shift,
                            int C, float invN)
{
    int c = blockIdx.x * blockDim.x + threadIdx.x;
    if (c < C) {
        float m   = sum[c] * invN;
        float var = fmaf(-m, m, sq[c] * invN);
        float rs  = rsqrtf(var + EPS);
        float sc  = rs * g[c];
        scale[c] = sc;
        shift[c] = fmaf(-m, sc, be[c]);
    }
}

extern "C" void kernel_launch(void* const* d_in, const int* in_sizes, int n_in,
                              void* d_out, int out_size, void* d_ws, size_t ws_size,
                              hipStream_t stream) {
    const float* feats = (const float*)d_in[0];
    const float* skip1 = (const float*)d_in[1];
    const float* skip2 = (const float*)d_in[2];
    const float* skip3 = (const float*)d_in[3];
    const int*   idx1  = (const int*)d_in[4];
    const int*   idx2  = (const int*)d_in[5];
    const int*   idx3  = (const int*)d_in[6];
    const float* W1    = (const float*)d_in[7];
    const float* b1    = (const float*)d_in[8];
    const float* g1    = (const float*)d_in[9];
    const float* be1   = (const float*)d_in[10];
    const float* W2    = (const float*)d_in[11];
    const float* b2    = (const float*)d_in[12];
    const float* g2    = (const float*)d_in[13];
    const float* be2   = (const float*)d_in[14];
    const float* W3    = (const float*)d_in[15];
    const float* b3    = (const float*)d_in[16];

    float* ws   = (float*)d_ws;
    float* sum1 = ws;        float* sq1 = ws + 256;
    float* sc1  = ws + 512;  float* sh1 = ws + 768;
    float* sum2 = ws + 1024; float* sq2 = ws + 1280;
    float* sc2  = ws + 1536; float* sh2 = ws + 1792;
    short* Wt1  = (short*)(ws + 2048);        // 144*800
    short* Wt2  = Wt1 + 144 * 800;            // 64*416
    short* Wt3  = Wt2 + 64 * 416;             // 48*192
    float* y1   = ws + 2048 + (144 * 800 + 64 * 416 + 48 * 192) / 2;  // [16384][132]
    float* y2   = y1 + 16384 * 132;                                   // [65536][64]
    float* outp = (float*)d_out;

    prep<<<450, 256, 0, stream>>>(W1, W2, W3, Wt1, Wt2, Wt3, ws);

    // stage 1: M=16384, K: feats(258->9 tiles) + skip3(512->16), N=129 (9 ntiles)
    mfma_stage<258, 258, 9, 512, 16, 9, 129, 132, 8, false, true>
        <<<256, 256, 0, stream>>>(feats, skip3, idx1, Wt1, b1,
                                  nullptr, nullptr, y1, sum1, sq1);
    finalize_bn<<<1, 256, 0, stream>>>(sum1, sq1, g1, be1, sc1, sh1,
                                       129, 1.f / 16384.f);

    // stage 2: M=65536, K: y1(129->5 tiles) + skip2(256->8), N=64 (4 ntiles)
    mfma_stage<132, 129, 5, 256, 8, 4, 64, 64, 16, true, true>
        <<<1024, 256, 0, stream>>>(y1, skip2, idx2, Wt2, b2,
                                   sc1, sh1, y2, sum2, sq2);
    finalize_bn<<<1, 256, 0, stream>>>(sum2, sq2, g2, be2, sc2, sh2,
                                       64, 1.f / 65536.f);

    // stage 3: M=262144, K: y2(64->2 tiles) + skip1(128->4), N=34 (3 ntiles)
    mfma_stage<64, 64, 2, 128, 4, 3, 34, 34, 16, true, false>
        <<<4096, 256, 0, stream>>>(y2, skip1, idx3, Wt3, b3,
                                   sc2, sh2, outp, nullptr, nullptr);
}

// Round 3
// 163.947 us; speedup vs baseline: 10.7262x; 1.1905x over previous
//
#include <hip/hip_runtime.h>

#define EPS 1e-5f
#define SLOPE 0.01f

typedef __attribute__((ext_vector_type(2))) float f32x2;
typedef __attribute__((ext_vector_type(4))) float f32x4;
typedef __attribute__((ext_vector_type(8))) short bf16x8;

__device__ __forceinline__ short f2bf(float f) {
    unsigned u = __float_as_uint(f);
    unsigned r = (u + 0x7FFFu + ((u >> 16) & 1u)) >> 16;
    return (short)r;
}
__device__ __forceinline__ float lrelu(float v) { return v >= 0.f ? v : SLOPE * v; }

// ---------------------------------------------------------------------------
// Wt prep: transpose W -> Wt[n][kv] (bf16), zero-padded in both n and kv.
//  S1: kv 0..257 = W1 rows 0..257 (feats), 258..287 = 0, 288..799 = rows 258..769
//  S2: kv 0..128 = W2 rows 0..128 (y1),    129..159 = 0, 160..415 = rows 129..384
//  S3: kv 0..191 = W3 rows (exact, no pad)
// Also zeros the 2048-float stats block each call.
// ---------------------------------------------------------------------------
__global__ void prep(const float* __restrict__ W1, const float* __restrict__ W2,
                     const float* __restrict__ W3,
                     short* __restrict__ Wt1, short* __restrict__ Wt2,
                     short* __restrict__ Wt3, float* __restrict__ stats)
{
    int id = blockIdx.x * 256 + threadIdx.x;
    if (id < 2048) stats[id] = 0.f;
    if (id < 144 * 800) {
        int n = id / 800, kv = id - n * 800;
        float v = 0.f; int ks = -1;
        if (kv < 258) ks = kv; else if (kv >= 288) ks = 258 + (kv - 288);
        if (ks >= 0 && n < 129) v = W1[ks * 129 + n];
        Wt1[n * 800 + kv] = f2bf(v);
    }
    if (id < 64 * 416) {
        int n = id / 416, kv = id - n * 416;
        float v = 0.f; int ks = -1;
        if (kv < 129) ks = kv; else if (kv >= 160) ks = 129 + (kv - 160);
        if (ks >= 0) v = W2[ks * 64 + n];
        Wt2[n * 416 + kv] = f2bf(v);
    }
    if (id < 48 * 192) {
        int n = id / 192, kv = id - n * 192;
        float v = 0.f;
        if (n < 34) v = W3[kv * 34 + n];
        Wt3[n * 192 + kv] = f2bf(v);
    }
}

// ---------------------------------------------------------------------------
// MFMA stage, ILP-restructured: tiles are processed in chunks of PF; per chunk
// all A-region loads are issued first into registers (pf[][]) so PF*2
// independent 16B loads are in flight, then BN+cvt+MFMA consume them.
// Virtual K layout: tile t<XT = gathered x (+BN), t>=XT = own skip row; Wt is
// contiguous in virtual kv = t*32.
// ---------------------------------------------------------------------------
template<int XD, int XVALID, int XT, int SD, int ST, int NT, int NVALID, int OD,
         int XALIGN, int PF, bool BN, bool STATS>
__global__ __launch_bounds__(256, 4)
void mfma_stage(const float* __restrict__ xsrc, const float* __restrict__ skip,
                const int* __restrict__ idx, const short* __restrict__ Wt,
                const float* __restrict__ bias,
                const float* __restrict__ bnsc, const float* __restrict__ bnsh,
                float* __restrict__ out, float* __restrict__ ssum,
                float* __restrict__ ssq)
{
    constexpr int KV = 32 * (XT + ST);
    constexpr int T = XT + ST;
    constexpr int NC = (T + PF - 1) / PF;
    constexpr int NPAD = NT * 16;
    __shared__ float ls[STATS ? 2 * NPAD : 1];

    const int tid = threadIdx.x;
    const int wave = tid >> 6, lane = tid & 63;
    const int lr = lane & 15;                    // A row-in-16 / D col
    const int kg = lane >> 4;                    // k-group
    const int row16 = (blockIdx.x * 4 + wave) * 16;
    const int n0 = blockIdx.y * NPAD;
    const int myrow = row16 + lr;
    const int grow = idx[myrow];
    const float* xrow = xsrc + grow * XD;
    const float* srow = skip + myrow * SD;
    const short* wtl = Wt + (n0 + lr) * KV;

    if (STATS) {
        for (int i = tid; i < 2 * NPAD; i += 256) ls[i] = 0.f;
        __syncthreads();
    }

    f32x4 acc[NT];
#pragma unroll
    for (int nt = 0; nt < NT; ++nt) acc[nt] = (f32x4){0.f, 0.f, 0.f, 0.f};

    float pf[PF][8];

#pragma unroll
    for (int c = 0; c < NC; ++c) {
        // ---- phase 1: issue all loads of this chunk ----
#pragma unroll
        for (int g = 0; g < PF; ++g) {
            const int t = c * PF + g;
            if (t >= T) continue;
            const int kb = (t < XT) ? (t * 32 + kg * 8) : ((t - XT) * 32 + kg * 8);
            const float* src = (t < XT) ? (xrow + kb) : (srow + kb);
            const bool full = (t >= XT) || ((t + 1) * 32 <= XVALID);
            if (full) {
                if (t >= XT || XALIGN >= 16) {
                    f32x4 a0 = *(const f32x4*)(src);
                    f32x4 a1 = *(const f32x4*)(src + 4);
#pragma unroll
                    for (int e = 0; e < 4; ++e) { pf[g][e] = a0[e]; pf[g][e + 4] = a1[e]; }
                } else if (XALIGN >= 8) {
#pragma unroll
                    for (int h = 0; h < 4; ++h) {
                        f32x2 a0 = *(const f32x2*)(src + 2 * h);
                        pf[g][2 * h] = a0[0]; pf[g][2 * h + 1] = a0[1];
                    }
                } else {
#pragma unroll
                    for (int e = 0; e < 8; ++e) pf[g][e] = src[e];
                }
            } else {  // partial boundary tile: guarded scalar loads, zeros pad
#pragma unroll
                for (int e = 0; e < 8; ++e)
                    pf[g][e] = (kb + e < XVALID) ? src[e] : 0.f;
            }
        }
        // ---- phase 2: BN + cvt + MFMA ----
#pragma unroll
        for (int g = 0; g < PF; ++g) {
            const int t = c * PF + g;
            if (t >= T) continue;
            const int kb = (t < XT) ? (t * 32 + kg * 8) : ((t - XT) * 32 + kg * 8);
            float v[8];
#pragma unroll
            for (int e = 0; e < 8; ++e) v[e] = pf[g][e];
            if (BN && t < XT) {
                if ((t + 1) * 32 <= XVALID) {
                    f32x4 c0 = *(const f32x4*)(bnsc + kb);
                    f32x4 c1 = *(const f32x4*)(bnsc + kb + 4);
                    f32x4 h0 = *(const f32x4*)(bnsh + kb);
                    f32x4 h1 = *(const f32x4*)(bnsh + kb + 4);
#pragma unroll
                    for (int e = 0; e < 4; ++e) {
                        v[e]     = lrelu(fmaf(v[e],     c0[e], h0[e]));
                        v[e + 4] = lrelu(fmaf(v[e + 4], c1[e], h1[e]));
                    }
                } else {
#pragma unroll
                    for (int e = 0; e < 8; ++e)
                        if (kb + e < XVALID)
                            v[e] = lrelu(fmaf(v[e], bnsc[kb + e], bnsh[kb + e]));
                }
            }
            bf16x8 a;
#pragma unroll
            for (int e = 0; e < 8; ++e) a[e] = f2bf(v[e]);
            const short* wk = wtl + t * 32 + kg * 8;   // virtual kv
#pragma unroll
            for (int nt = 0; nt < NT; ++nt) {
                bf16x8 b = *(const bf16x8*)(wk + nt * 16 * KV);
                acc[nt] = __builtin_amdgcn_mfma_f32_16x16x32_bf16(a, b, acc[nt], 0, 0, 0);
            }
        }
    }

    // ---- bias, store, stats ----
#pragma unroll
    for (int nt = 0; nt < NT; ++nt) {
        const int n = n0 + nt * 16 + lr;
        const float bv = (n < NVALID) ? bias[n] : 0.f;
        f32x4 y = acc[nt];
#pragma unroll
        for (int r = 0; r < 4; ++r) y[r] += bv;
        if (n < NVALID) {
#pragma unroll
            for (int r = 0; r < 4; ++r)
                out[(row16 + kg * 4 + r) * OD + n] = y[r];
        }
        if (STATS) {
            float s = y[0] + y[1] + y[2] + y[3];
            float q = y[0]*y[0] + y[1]*y[1] + y[2]*y[2] + y[3]*y[3];
            s += __shfl_xor(s, 16, 64);
            s += __shfl_xor(s, 32, 64);
            q += __shfl_xor(q, 16, 64);
            q += __shfl_xor(q, 32, 64);
            if (lane < 16) {
                atomicAdd(&ls[nt * 16 + lr], s);
                atomicAdd(&ls[NPAD + nt * 16 + lr], q);
            }
        }
    }
    if (STATS) {
        __syncthreads();
        if (tid < NPAD) {
            atomicAdd(&ssum[n0 + tid], ls[tid]);
            atomicAdd(&ssq[n0 + tid], ls[NPAD + tid]);
        }
    }
}

__global__ void finalize_bn(const float* __restrict__ sum,
                            const float* __restrict__ sq,
                            const float* __restrict__ g,
                            const float* __restrict__ be,
                            float* __restrict__ scale,
                            float* __restrict__ shift,
                            int C, float invN)
{
    int c = blockIdx.x * blockDim.x + threadIdx.x;
    if (c < C) {
        float m   = sum[c] * invN;
        float var = fmaf(-m, m, sq[c] * invN);
        float rs  = rsqrtf(var + EPS);
        float sc  = rs * g[c];
        scale[c] = sc;
        shift[c] = fmaf(-m, sc, be[c]);
    }
}

extern "C" void kernel_launch(void* const* d_in, const int* in_sizes, int n_in,
                              void* d_out, int out_size, void* d_ws, size_t ws_size,
                              hipStream_t stream) {
    const float* feats = (const float*)d_in[0];
    const float* skip1 = (const float*)d_in[1];
    const float* skip2 = (const float*)d_in[2];
    const float* skip3 = (const float*)d_in[3];
    const int*   idx1  = (const int*)d_in[4];
    const int*   idx2  = (const int*)d_in[5];
    const int*   idx3  = (const int*)d_in[6];
    const float* W1    = (const float*)d_in[7];
    const float* b1    = (const float*)d_in[8];
    const float* g1    = (const float*)d_in[9];
    const float* be1   = (const float*)d_in[10];
    const float* W2    = (const float*)d_in[11];
    const float* b2    = (const float*)d_in[12];
    const float* g2    = (const float*)d_in[13];
    const float* be2   = (const float*)d_in[14];
    const float* W3    = (const float*)d_in[15];
    const float* b3    = (const float*)d_in[16];

    float* ws   = (float*)d_ws;
    float* sum1 = ws;        float* sq1 = ws + 256;
    float* sc1  = ws + 512;  float* sh1 = ws + 768;
    float* sum2 = ws + 1024; float* sq2 = ws + 1280;
    float* sc2  = ws + 1536; float* sh2 = ws + 1792;
    short* Wt1  = (short*)(ws + 2048);        // 144*800
    short* Wt2  = Wt1 + 144 * 800;            // 64*416
    short* Wt3  = Wt2 + 64 * 416;             // 48*192
    float* y1   = ws + 2048 + (144 * 800 + 64 * 416 + 48 * 192) / 2;  // [16384][132]
    float* y2   = y1 + 16384 * 132;                                   // [65536][64]
    float* outp = (float*)d_out;

    prep<<<450, 256, 0, stream>>>(W1, W2, W3, Wt1, Wt2, Wt3, ws);

    // stage 1: M=16384, K: feats(258->9 tiles)+skip3(512->16), N=129, 3 n-chunks
    mfma_stage<258, 258, 9, 512, 16, 3, 129, 132, 8, 8, false, true>
        <<<dim3(256, 3), 256, 0, stream>>>(feats, skip3, idx1, Wt1, b1,
                                           nullptr, nullptr, y1, sum1, sq1);
    finalize_bn<<<1, 256, 0, stream>>>(sum1, sq1, g1, be1, sc1, sh1,
                                       129, 1.f / 16384.f);

    // stage 2: M=65536, K: y1(129->5 tiles) + skip2(256->8), N=64 (4 ntiles)
    mfma_stage<132, 129, 5, 256, 8, 4, 64, 64, 16, 7, true, true>
        <<<dim3(1024, 1), 256, 0, stream>>>(y1, skip2, idx2, Wt2, b2,
                                            sc1, sh1, y2, sum2, sq2);
    finalize_bn<<<1, 256, 0, stream>>>(sum2, sq2, g2, be2, sc2, sh2,
                                       64, 1.f / 65536.f);

    // stage 3: M=262144, K: y2(64->2 tiles) + skip1(128->4), N=34 (3 ntiles)
    mfma_stage<64, 64, 2, 128, 4, 3, 34, 34, 16, 6, true, false>
        <<<dim3(4096, 1), 256, 0, stream>>>(y2, skip1, idx3, Wt3, b3,
                                            sc2, sh2, outp, nullptr, nullptr);
}